// Round 19
// baseline (31.683 us; speedup 1.0000x reference)
//
#include <hip/hip_runtime.h>

#define BATCH 16
#define NPTS 4096
#define TOTN (BATCH * NPTS)    // 65536
#define STAGE 1024             // m staged in LDS at a time
#define NSTAGE (NPTS / STAGE)  // 4

typedef _Float16 f16;
typedef __attribute__((ext_vector_type(8))) _Float16 f16x8;
typedef __attribute__((ext_vector_type(16))) float f32x16;

__device__ __forceinline__ unsigned pk(f16 a, f16 b) {
    union { f16 h[2]; unsigned u; } t;
    t.h[0] = a; t.h[1] = b;   // h[0] -> low 16 bits = even k slot
    return t.u;
}

__device__ __forceinline__ float min3f(float a, float b, float c) {
    return fminf(fminf(a, b), c);   // clang fuses to v_min3_f32
}

__device__ __forceinline__ float treemin(const f32x16& d, float acc) {
    float t0 = min3f(d[0], d[1], d[2]);
    float t1 = min3f(d[3], d[4], d[5]);
    float t2 = min3f(d[6], d[7], d[8]);
    float t3 = min3f(d[9], d[10], d[11]);
    float t4 = min3f(d[12], d[13], d[14]);
    float u0 = min3f(t0, t1, t2);
    float u1 = min3f(t3, t4, d[15]);
    return min3f(acc, u0, u1);
}

// Launch 1: zero the atomic accumulator (stream order guarantees visibility).
__global__ void reset_kernel(float* __restrict__ out) { out[0] = 0.0f; }

// Launch 2 (fused): grid = BATCH*32 = 512 blocks (2/CU). Block = (batch,
// 128-n group); 4 waves, each owning ONE 32-col tile. ALL 4096 m pass through
// LDS in 4 stages of 1024 (32 KB); next stage's global loads are issued
// right after the barrier so they fly under the current stage's 32 MFMA
// iterations (async-stage split). Min finishes in-block -> +|a_n|^2 ->
// wave-sum -> one atomicAdd per block. No partials, no combine pass.
// A-side k-slots (c = -2 p_m, b2 = |p_m|^2):
//   k0..8 = [cxh,cxh,cxl, cyh,cyh,cyl, czh,czh,czl], k9,k10 = [b2h,b2l]
// B-side (a_n = mirrored point): k0..8 = [axh,axl,axh, ayh,ayl,ayh, azh,azl,azh],
//   k9,k10 = [1,1]  =>  D[m][n] = |p_m|^2 - 2 a_n.p_m  (err ~2^-22)
__global__ __launch_bounds__(256) void fused_chamfer_kernel(
    const float* __restrict__ xyz, float* __restrict__ out) {
    __shared__ uint4 T0[STAGE];   // A-frag k0..7  (16 KB)
    __shared__ uint4 T1[STAGE];   // A-frag k8..15 (16 KB)
    __shared__ float red[4];

    const int tid = threadIdx.x;
    const int lane = tid & 63;
    const int wid = tid >> 6;
    const int lm = lane & 31;
    const int kh = lane >> 5;          // which k-half this lane supplies

    const int b = blockIdx.x >> 5;
    const int ng = blockIdx.x & 31;    // 128-n group
    const float* base = xyz + (size_t)b * 3 * NPTS;

    // B-side fragment for this wave's single 32-col tile.
    const int n = ng * 128 + wid * 32 + lm;
    const float ax = -base[n];         // mirror across yz-plane
    const float ay = base[NPTS + n];
    const float az = base[2 * NPTS + n];
    const float a2 = fmaf(ax, ax, fmaf(ay, ay, az * az));
    f16x8 Bf;
    {
        f16 axh = (f16)ax, axl = (f16)(ax - (float)axh);
        f16 ayh = (f16)ay, ayl = (f16)(ay - (float)ayh);
        f16 azh = (f16)az, azl = (f16)(az - (float)azh);
        union { unsigned u[4]; f16x8 v; } B;
        if (kh == 0) {
            B.u[0] = pk(axh, axl); B.u[1] = pk(axh, ayh);
            B.u[2] = pk(ayl, ayh); B.u[3] = pk(azh, azl);
        } else {
            B.u[0] = pk(azh, (f16)1.f); B.u[1] = pk((f16)1.f, (f16)0.f);
            B.u[2] = 0u; B.u[3] = 0u;
        }
        Bf = B.v;
    }

    // Prefetch stage 0 (4 m per thread, coalesced per j).
    float sx[4], sy[4], sz[4];
#pragma unroll
    for (int j = 0; j < 4; ++j) {
        int mg = tid + j * 256;
        sx[j] = base[mg]; sy[j] = base[NPTS + mg]; sz[j] = base[2 * NPTS + mg];
    }

    float acc = 1e30f;
    const f32x16 zero = {};

    for (int s = 0; s < NSTAGE; ++s) {
        __syncthreads();               // prior stage's reads complete
        // Convert + write this stage's A-frags to LDS.
#pragma unroll
        for (int j = 0; j < 4; ++j) {
            int i = tid + j * 256;
            float x = sx[j], y = sy[j], z = sz[j];
            float cx = -2.f * x, cy = -2.f * y, cz = -2.f * z;
            float b2 = fmaf(x, x, fmaf(y, y, z * z));
            f16 cxh = (f16)cx, cxl = (f16)(cx - (float)cxh);
            f16 cyh = (f16)cy, cyl = (f16)(cy - (float)cyh);
            f16 czh = (f16)cz, czl = (f16)(cz - (float)czh);
            f16 b2h = (f16)b2, b2l = (f16)(b2 - (float)b2h);
            T0[i] = make_uint4(pk(cxh, cxh), pk(cxl, cyh), pk(cyh, cyl), pk(czh, czh));
            T1[i] = make_uint4(pk(czl, b2h), pk(b2l, (f16)0.f), 0u, 0u);
        }
        __syncthreads();
        // Issue next stage's global loads now; they complete under the MFMAs.
        if (s + 1 < NSTAGE) {
#pragma unroll
            for (int j = 0; j < 4; ++j) {
                int mg = (s + 1) * STAGE + tid + j * 256;
                sx[j] = base[mg]; sy[j] = base[NPTS + mg]; sz[j] = base[2 * NPTS + mg];
            }
        }

        const uint4* Ab = kh ? T1 : T0;
#pragma unroll 4
        for (int t = 0; t < STAGE / 32; ++t) {
            union { uint4 q; f16x8 v; } A;
            A.q = Ab[t * 32 + lm];     // row m = t*32 + lm, this lane's k-half
            f32x16 d = __builtin_amdgcn_mfma_f32_32x32x16_f16(A.v, Bf, zero, 0, 0, 0);
            acc = treemin(d, acc);
        }
    }

    // Combine row-halves; lanes 0-31 now hold the true per-col min.
    acc = fminf(acc, __shfl_xor(acc, 32, 64));
    float val = (lane < 32) ? (acc + a2) : 0.0f;
#pragma unroll
    for (int off = 32; off; off >>= 1) val += __shfl_down(val, off, 64);
    if (lane == 0) red[wid] = val;
    __syncthreads();
    if (tid == 0)
        atomicAdd(out, ((red[0] + red[1]) + (red[2] + red[3])) * (2.0f / (float)TOTN));
}

extern "C" void kernel_launch(void* const* d_in, const int* in_sizes, int n_in,
                              void* d_out, int out_size, void* d_ws, size_t ws_size,
                              hipStream_t stream) {
    const float* xyz = (const float*)d_in[0];
    float* out = (float*)d_out;

    reset_kernel<<<1, 1, 0, stream>>>(out);
    fused_chamfer_kernel<<<BATCH * 32, 256, 0, stream>>>(xyz, out);
}

// Round 22
// 18.247 us; speedup vs baseline: 1.7364x; 1.7364x over previous
//
#include <hip/hip_runtime.h>

#define BATCH 16
#define NPTS 4096
#define TOTN (BATCH * NPTS)   // 65536
#define MH 4                  // m-chunks per batch
#define MC (NPTS / MH)        // 1024 m per block

typedef _Float16 f16;
typedef __attribute__((ext_vector_type(8))) _Float16 f16x8;
typedef __attribute__((ext_vector_type(16))) float f32x16;

__device__ __forceinline__ unsigned pk(f16 a, f16 b) {
    union { f16 h[2]; unsigned u; } t;
    t.h[0] = a; t.h[1] = b;   // h[0] -> low 16 bits = even k slot
    return t.u;
}

__device__ __forceinline__ float min3f(float a, float b, float c) {
    return fminf(fminf(a, b), c);   // clang fuses to v_min3_f32
}

// Min over the 16 C/D regs (rows of one 32-col tile) then into acc: 8x min3.
__device__ __forceinline__ float treemin(const f32x16& d, float acc) {
    float t0 = min3f(d[0], d[1], d[2]);
    float t1 = min3f(d[3], d[4], d[5]);
    float t2 = min3f(d[6], d[7], d[8]);
    float t3 = min3f(d[9], d[10], d[11]);
    float t4 = min3f(d[12], d[13], d[14]);
    float u0 = min3f(t0, t1, t2);
    float u1 = min3f(t3, t4, d[15]);
    return min3f(acc, u0, u1);
}

// Grid = BATCH * 8 nsup * MH = 512 blocks (2/CU, 8 waves/CU), 32 KB LDS.
// Wave owns 128 n = 4 column-tiles of 32: per m-iter ONE ds_read_b128 feeds
// 4 independent MFMAs + 4 treemins (max ILP per LDS instruction).
// Also zeroes out[0] for the atomic tail (stream order guarantees visibility).
// A-side k-slots (c = -2 p_m, b2 = |p_m|^2):
//   k0..8 = [cxh,cxh,cxl, cyh,cyh,cyl, czh,czh,czl], k9,k10 = [b2h,b2l]
// B-side (a_n = mirrored point): k0..8 = [axh,axl,axh, ayh,ayl,ayh, azh,azl,azh],
//   k9,k10 = [1,1]  =>  D[m][n] = |p_m|^2 - 2 a_n.p_m  (err ~2^-22)
__global__ __launch_bounds__(256, 4) void chamfer_mfma_kernel(
    const float* __restrict__ xyz, float* __restrict__ partials,
    float* __restrict__ out) {
    __shared__ uint4 T0[MC];   // A-frag k0..7  per m (16 KB)
    __shared__ uint4 T1[MC];   // A-frag k8..15 per m (16 KB)

    const int tid = threadIdx.x;
    if (blockIdx.x == 0 && tid == 0) out[0] = 0.0f;   // reset accumulator

    const int lane = tid & 63;
    const int wid = tid >> 6;
    const int lm = lane & 31;
    const int kh = lane >> 5;          // which k-half this lane supplies

    const int mh = blockIdx.x & (MH - 1);
    const int nsup = (blockIdx.x >> 2) & 7;
    const int b = blockIdx.x >> 5;
    const float* base = xyz + (size_t)b * 3 * NPTS;

    // Stage expanded A-side fragments for this block's 1024 m.
    const int m0 = mh * MC;
    for (int i = tid; i < MC; i += 256) {
        int mg = m0 + i;
        float x = base[mg], y = base[NPTS + mg], z = base[2 * NPTS + mg];
        float cx = -2.f * x, cy = -2.f * y, cz = -2.f * z;
        float b2 = fmaf(x, x, fmaf(y, y, z * z));
        f16 cxh = (f16)cx, cxl = (f16)(cx - (float)cxh);
        f16 cyh = (f16)cy, cyl = (f16)(cy - (float)cyh);
        f16 czh = (f16)cz, czl = (f16)(cz - (float)czh);
        f16 b2h = (f16)b2, b2l = (f16)(b2 - (float)b2h);
        T0[i] = make_uint4(pk(cxh, cxh), pk(cxl, cyh), pk(cyh, cyl), pk(czh, czh));
        T1[i] = make_uint4(pk(czl, b2h), pk(b2l, (f16)0.f), 0u, 0u);
    }
    __syncthreads();

    // B-side fragments for this wave's four 32-n tiles.
    const int n0 = nsup * 512 + wid * 128;
    f16x8 Bf[4];
#pragma unroll
    for (int tile = 0; tile < 4; ++tile) {
        int n = n0 + tile * 32 + lm;
        float ax = -base[n];               // mirror across yz-plane
        float ay = base[NPTS + n];
        float az = base[2 * NPTS + n];
        f16 axh = (f16)ax, axl = (f16)(ax - (float)axh);
        f16 ayh = (f16)ay, ayl = (f16)(ay - (float)ayh);
        f16 azh = (f16)az, azl = (f16)(az - (float)azh);
        union { unsigned u[4]; f16x8 v; } B;
        if (kh == 0) {
            B.u[0] = pk(axh, axl); B.u[1] = pk(axh, ayh);
            B.u[2] = pk(ayl, ayh); B.u[3] = pk(azh, azl);
        } else {
            B.u[0] = pk(azh, (f16)1.f); B.u[1] = pk((f16)1.f, (f16)0.f);
            B.u[2] = 0u; B.u[3] = 0u;
        }
        Bf[tile] = B.v;
    }

    const uint4* Ab = kh ? T1 : T0;    // uniform instruction, per-lane base
    float acc0 = 1e30f, acc1 = 1e30f, acc2 = 1e30f, acc3 = 1e30f;
    const f32x16 zero = {};

#pragma unroll 2
    for (int t = 0; t < MC / 32; ++t) {
        union { uint4 q; f16x8 v; } A;
        A.q = Ab[t * 32 + lm];         // row m = t*32 + lm, this lane's k-half
        f32x16 d0 = __builtin_amdgcn_mfma_f32_32x32x16_f16(A.v, Bf[0], zero, 0, 0, 0);
        f32x16 d1 = __builtin_amdgcn_mfma_f32_32x32x16_f16(A.v, Bf[1], zero, 0, 0, 0);
        f32x16 d2 = __builtin_amdgcn_mfma_f32_32x32x16_f16(A.v, Bf[2], zero, 0, 0, 0);
        f32x16 d3 = __builtin_amdgcn_mfma_f32_32x32x16_f16(A.v, Bf[3], zero, 0, 0, 0);
        acc0 = treemin(d0, acc0);
        acc1 = treemin(d1, acc1);
        acc2 = treemin(d2, acc2);
        acc3 = treemin(d3, acc3);
    }

    // Combine row-halves (lane vs lane^32 hold complementary rows of each col).
    acc0 = fminf(acc0, __shfl_xor(acc0, 32, 64));
    acc1 = fminf(acc1, __shfl_xor(acc1, 32, 64));
    acc2 = fminf(acc2, __shfl_xor(acc2, 32, 64));
    acc3 = fminf(acc3, __shfl_xor(acc3, 32, 64));

    // Full-wave store: lanes 0-31 write acc0/acc2, lanes 32-63 write acc1/acc3.
    float* dst = partials + (size_t)mh * TOTN + b * NPTS + n0;
    dst[kh * 32 + lm] = kh ? acc1 : acc0;
    dst[64 + kh * 32 + lm] = kh ? acc3 : acc2;
}

// Pass 2 (tail): 4 n per thread via float4; min over MH chunks, add |a_n|^2,
// block-sum 1024 n's, one scaled float atomicAdd into out[0] per block.
__global__ __launch_bounds__(256) void combine_kernel(
    const float* __restrict__ xyz, const float* __restrict__ partials,
    float* __restrict__ out) {
    __shared__ float red[4];
    const int n0 = (blockIdx.x * 256 + threadIdx.x) * 4;   // 0..TOTN-4
    float4 v = *reinterpret_cast<const float4*>(&partials[n0]);
#pragma unroll
    for (int s = 1; s < MH; ++s) {
        float4 p = *reinterpret_cast<const float4*>(&partials[(size_t)s * TOTN + n0]);
        v.x = fminf(v.x, p.x); v.y = fminf(v.y, p.y);
        v.z = fminf(v.z, p.z); v.w = fminf(v.w, p.w);
    }

    const int b = n0 >> 12;
    const int i = n0 & (NPTS - 1);
    const float* base = xyz + (size_t)b * 3 * NPTS;
    float4 xv = *reinterpret_cast<const float4*>(&base[i]);
    float4 yv = *reinterpret_cast<const float4*>(&base[NPTS + i]);
    float4 zv = *reinterpret_cast<const float4*>(&base[2 * NPTS + i]);

    float s0 = v.x + fmaf(xv.x, xv.x, fmaf(yv.x, yv.x, zv.x * zv.x));
    float s1 = v.y + fmaf(xv.y, xv.y, fmaf(yv.y, yv.y, zv.y * zv.y));
    float s2 = v.z + fmaf(xv.z, xv.z, fmaf(yv.z, yv.z, zv.z * zv.z));
    float s3 = v.w + fmaf(xv.w, xv.w, fmaf(yv.w, yv.w, zv.w * zv.w));
    float sum = (s0 + s1) + (s2 + s3);

#pragma unroll
    for (int off = 32; off; off >>= 1) sum += __shfl_down(sum, off, 64);
    if ((threadIdx.x & 63) == 0) red[threadIdx.x >> 6] = sum;
    __syncthreads();
    if (threadIdx.x == 0) {
        float bs = (red[0] + red[1]) + (red[2] + red[3]);
        atomicAdd(out, bs * (2.0f / (float)TOTN));
    }
}

extern "C" void kernel_launch(void* const* d_in, const int* in_sizes, int n_in,
                              void* d_out, int out_size, void* d_ws, size_t ws_size,
                              hipStream_t stream) {
    const float* xyz = (const float*)d_in[0];
    float* out = (float*)d_out;
    float* partials = (float*)d_ws;                    // MH*TOTN floats (1 MB)

    chamfer_mfma_kernel<<<BATCH * 8 * MH, 256, 0, stream>>>(xyz, partials, out);
    combine_kernel<<<TOTN / 1024, 256, 0, stream>>>(xyz, partials, out);
}

// Round 24
// 17.620 us; speedup vs baseline: 1.7982x; 1.0356x over previous
//
#include <hip/hip_runtime.h>

#define BATCH 16
#define NPTS 4096
#define TOTN (BATCH * NPTS)   // 65536
#define MH 4                  // m-chunks per batch
#define MC (NPTS / MH)        // 1024 m per block

typedef _Float16 f16;
typedef __attribute__((ext_vector_type(8))) _Float16 f16x8;
typedef __attribute__((ext_vector_type(16))) float f32x16;

__device__ __forceinline__ unsigned pk(f16 a, f16 b) {
    union { f16 h[2]; unsigned u; } t;
    t.h[0] = a; t.h[1] = b;   // h[0] -> low 16 bits = even k slot
    return t.u;
}

__device__ __forceinline__ float min3f(float a, float b, float c) {
    return fminf(fminf(a, b), c);   // clang fuses to v_min3_f32
}

// Min over the 16 C/D regs (rows of one 32-col tile) then into acc: 8x min3.
__device__ __forceinline__ float treemin(const f32x16& d, float acc) {
    float t0 = min3f(d[0], d[1], d[2]);
    float t1 = min3f(d[3], d[4], d[5]);
    float t2 = min3f(d[6], d[7], d[8]);
    float t3 = min3f(d[9], d[10], d[11]);
    float t4 = min3f(d[12], d[13], d[14]);
    float u0 = min3f(t0, t1, t2);
    float u1 = min3f(t3, t4, d[15]);
    return min3f(acc, u0, u1);
}

// BEST KNOWN (R18, 17.76 us): Grid = BATCH * 16 nsup * MH = 1024 blocks,
// (256,4), 32 KB LDS -> 4 blocks/CU. Wave owns 64 n = 2 column-tiles of 32;
// 64 m-iters per block. Launch 1 zeroes out[0] for the atomic tail.
// A-side k-slots (c = -2 p_m, b2 = |p_m|^2):
//   k0..8 = [cxh,cxh,cxl, cyh,cyh,cyl, czh,czh,czl], k9,k10 = [b2h,b2l]
// B-side (a_n = mirrored point): k0..8 = [axh,axl,axh, ayh,ayl,ayh, azh,azl,azh],
//   k9,k10 = [1,1]  =>  D[m][n] = |p_m|^2 - 2 a_n.p_m  (err ~2^-22)
__global__ __launch_bounds__(256, 4) void chamfer_mfma_kernel(
    const float* __restrict__ xyz, float* __restrict__ partials,
    float* __restrict__ out) {
    __shared__ uint4 T0[MC];   // A-frag k0..7  per m (16 KB)
    __shared__ uint4 T1[MC];   // A-frag k8..15 per m (16 KB)

    const int tid = threadIdx.x;
    if (blockIdx.x == 0 && tid == 0) out[0] = 0.0f;   // reset accumulator

    const int lane = tid & 63;
    const int wid = tid >> 6;
    const int lm = lane & 31;
    const int kh = lane >> 5;          // which k-half this lane supplies

    const int mh = blockIdx.x & (MH - 1);
    const int nsup = (blockIdx.x >> 2) & 15;
    const int b = blockIdx.x >> 6;
    const float* base = xyz + (size_t)b * 3 * NPTS;

    // Stage expanded A-side fragments for this block's 1024 m.
    const int m0 = mh * MC;
    for (int i = tid; i < MC; i += 256) {
        int mg = m0 + i;
        float x = base[mg], y = base[NPTS + mg], z = base[2 * NPTS + mg];
        float cx = -2.f * x, cy = -2.f * y, cz = -2.f * z;
        float b2 = fmaf(x, x, fmaf(y, y, z * z));
        f16 cxh = (f16)cx, cxl = (f16)(cx - (float)cxh);
        f16 cyh = (f16)cy, cyl = (f16)(cy - (float)cyh);
        f16 czh = (f16)cz, czl = (f16)(cz - (float)czh);
        f16 b2h = (f16)b2, b2l = (f16)(b2 - (float)b2h);
        T0[i] = make_uint4(pk(cxh, cxh), pk(cxl, cyh), pk(cyh, cyl), pk(czh, czh));
        T1[i] = make_uint4(pk(czl, b2h), pk(b2l, (f16)0.f), 0u, 0u);
    }
    __syncthreads();

    // B-side fragments for this wave's two 32-n tiles.
    const int n0 = nsup * 256 + wid * 64;
    f16x8 Bf[2];
#pragma unroll
    for (int tile = 0; tile < 2; ++tile) {
        int n = n0 + tile * 32 + lm;
        float ax = -base[n];               // mirror across yz-plane
        float ay = base[NPTS + n];
        float az = base[2 * NPTS + n];
        f16 axh = (f16)ax, axl = (f16)(ax - (float)axh);
        f16 ayh = (f16)ay, ayl = (f16)(ay - (float)ayh);
        f16 azh = (f16)az, azl = (f16)(az - (float)azh);
        union { unsigned u[4]; f16x8 v; } B;
        if (kh == 0) {
            B.u[0] = pk(axh, axl); B.u[1] = pk(axh, ayh);
            B.u[2] = pk(ayl, ayh); B.u[3] = pk(azh, azl);
        } else {
            B.u[0] = pk(azh, (f16)1.f); B.u[1] = pk((f16)1.f, (f16)0.f);
            B.u[2] = 0u; B.u[3] = 0u;
        }
        Bf[tile] = B.v;
    }

    const uint4* Ab = kh ? T1 : T0;    // uniform instruction, per-lane base
    float acc0 = 1e30f, acc1 = 1e30f;
    const f32x16 zero = {};

#pragma unroll 4
    for (int t = 0; t < MC / 32; ++t) {
        union { uint4 q; f16x8 v; } A;
        A.q = Ab[t * 32 + lm];         // row m = t*32 + lm, this lane's k-half
        f32x16 d0 = __builtin_amdgcn_mfma_f32_32x32x16_f16(A.v, Bf[0], zero, 0, 0, 0);
        f32x16 d1 = __builtin_amdgcn_mfma_f32_32x32x16_f16(A.v, Bf[1], zero, 0, 0, 0);
        acc0 = treemin(d0, acc0);
        acc1 = treemin(d1, acc1);
    }

    // Combine row-halves (lane vs lane^32 hold complementary rows of each col).
    acc0 = fminf(acc0, __shfl_xor(acc0, 32, 64));
    acc1 = fminf(acc1, __shfl_xor(acc1, 32, 64));

    // Full-wave store: lanes 0-31 write acc0 cols, lanes 32-63 write acc1 cols.
    float* dst = partials + (size_t)mh * TOTN + b * NPTS + n0;
    dst[kh * 32 + lm] = kh ? acc1 : acc0;
}

// Pass 2 (tail): 4 n per thread via float4; min over MH chunks, add |a_n|^2,
// block-sum 1024 n's, one scaled float atomicAdd into out[0] per block.
__global__ __launch_bounds__(256) void combine_kernel(
    const float* __restrict__ xyz, const float* __restrict__ partials,
    float* __restrict__ out) {
    __shared__ float red[4];
    const int n0 = (blockIdx.x * 256 + threadIdx.x) * 4;   // 0..TOTN-4
    float4 v = *reinterpret_cast<const float4*>(&partials[n0]);
#pragma unroll
    for (int s = 1; s < MH; ++s) {
        float4 p = *reinterpret_cast<const float4*>(&partials[(size_t)s * TOTN + n0]);
        v.x = fminf(v.x, p.x); v.y = fminf(v.y, p.y);
        v.z = fminf(v.z, p.z); v.w = fminf(v.w, p.w);
    }

    const int b = n0 >> 12;
    const int i = n0 & (NPTS - 1);
    const float* base = xyz + (size_t)b * 3 * NPTS;
    float4 xv = *reinterpret_cast<const float4*>(&base[i]);
    float4 yv = *reinterpret_cast<const float4*>(&base[NPTS + i]);
    float4 zv = *reinterpret_cast<const float4*>(&base[2 * NPTS + i]);

    float s0 = v.x + fmaf(xv.x, xv.x, fmaf(yv.x, yv.x, zv.x * zv.x));
    float s1 = v.y + fmaf(xv.y, xv.y, fmaf(yv.y, yv.y, zv.y * zv.y));
    float s2 = v.z + fmaf(xv.z, xv.z, fmaf(yv.z, yv.z, zv.z * zv.z));
    float s3 = v.w + fmaf(xv.w, xv.w, fmaf(yv.w, yv.w, zv.w * zv.w));
    float sum = (s0 + s1) + (s2 + s3);

#pragma unroll
    for (int off = 32; off; off >>= 1) sum += __shfl_down(sum, off, 64);
    if ((threadIdx.x & 63) == 0) red[threadIdx.x >> 6] = sum;
    __syncthreads();
    if (threadIdx.x == 0) {
        float bs = (red[0] + red[1]) + (red[2] + red[3]);
        atomicAdd(out, bs * (2.0f / (float)TOTN));
    }
}

extern "C" void kernel_launch(void* const* d_in, const int* in_sizes, int n_in,
                              void* d_out, int out_size, void* d_ws, size_t ws_size,
                              hipStream_t stream) {
    const float* xyz = (const float*)d_in[0];
    float* out = (float*)d_out;
    float* partials = (float*)d_ws;                    // MH*TOTN floats (1 MB)

    chamfer_mfma_kernel<<<BATCH * 16 * MH, 256, 0, stream>>>(xyz, partials, out);
    combine_kernel<<<TOTN / 1024, 256, 0, stream>>>(xyz, partials, out);
}